// Round 1
// baseline (2659.982 us; speedup 1.0000x reference)
//
#include <hip/hip_runtime.h>
#include <hip/hip_bf16.h>
#include <math.h>

#define N_NODES 50000
#define N_EDGES 800000
#define HID 128
#define NF 128
#define C3 384   // 3*H
#define SILU_SCALE (1.0f/0.6f)
#define INV_SQRT3 0.57735026918962576f
#define INV_SQRTH 0.08838834764831845f   // 1/sqrt(128)

typedef __bf16 bf16x8 __attribute__((ext_vector_type(8)));
typedef __bf16 bf16x4 __attribute__((ext_vector_type(4)));
typedef float  floatx4 __attribute__((ext_vector_type(4)));

// ---------------------------------------------------------------------------
// Cast + transpose We [128][384] f32 -> WeT [384][128] bf16 (B-operand layout:
// 8 consecutive k per lane = 16B contiguous load).
// ---------------------------------------------------------------------------
__global__ void cast_weT(const float* __restrict__ We, __bf16* __restrict__ WeT) {
    int o = blockIdx.x * 256 + threadIdx.x;   // 49152 total
    int n = o / NF, k = o % NF;
    WeT[o] = (__bf16)We[k * C3 + n];
}

// ---------------------------------------------------------------------------
// Node MLP: x_h = (silu(x@W1+b1)*SILU_SCALE) @ W2 + b2.  4 nodes per block.
// ---------------------------------------------------------------------------
__global__ void node_mlp(const float* __restrict__ x,  const float* __restrict__ W1,
                         const float* __restrict__ b1, const float* __restrict__ W2,
                         const float* __restrict__ b2, float* __restrict__ x_h) {
    __shared__ float xs[4][HID];
    __shared__ float hs[4][64];
    const int t = threadIdx.x;
    const int base = blockIdx.x * 4;

    #pragma unroll
    for (int it = 0; it < 2; ++it) {
        int f = it * 256 + t;
        xs[f / HID][f % HID] = x[(size_t)base * HID + f];
    }
    __syncthreads();
    {
        int g = t >> 6, m = t & 63;
        float sum = b1[m];
        #pragma unroll 8
        for (int k = 0; k < HID; ++k) sum += xs[g][k] * W1[k * 64 + m];
        float sig = 1.0f / (1.0f + __expf(-sum));
        hs[g][m] = sum * sig * SILU_SCALE;
    }
    __syncthreads();
    #pragma unroll
    for (int it = 0; it < 6; ++it) {
        int o  = it * 256 + t;           // 4*384 = 1536 outputs
        int nd = o / C3, c = o % C3;
        float sum = b2[c];
        #pragma unroll 8
        for (int k = 0; k < 64; ++k) sum += hs[nd][k] * W2[k * C3 + c];
        x_h[(size_t)(base + nd) * C3 + c] = sum;
    }
}

// ---------------------------------------------------------------------------
// Fused edge kernel: per 64-edge block, MFMA-GEMM rbf_h = edge_rbf@We (+be in
// epilogue), then gather x_h[j]/vec[j] and atomic-scatter into d_x/d_vec.
// Wave w owns edges [16w,16w+16) x all 384 cols -> 24 C-frags (96 VGPR acc).
// ---------------------------------------------------------------------------
__global__ __launch_bounds__(256)
void edge_kernel(const float* __restrict__ edge_rbf,
                 const __bf16* __restrict__ WeT,
                 const float* __restrict__ be,
                 const float* __restrict__ x_h,
                 const float* __restrict__ vec,
                 const float* __restrict__ edge_vector,
                 const int*   __restrict__ eidx,
                 float* __restrict__ d_x, float* __restrict__ d_vec) {
    // LDS A-tile: 64 edges x 128 bf16, row stride 136 (pad 8) so the 16 lanes
    // of a quad reading stride-272B land 2-per-bank (free) instead of 16-way.
    __shared__ __bf16 Ash[64][136];
    const int t = threadIdx.x;
    const long e0 = (long)blockIdx.x * 64;

    // Stage edge_rbf[e0:e0+64][0:128] f32 -> bf16 LDS (coalesced float4 loads)
    #pragma unroll
    for (int it = 0; it < 8; ++it) {
        int fidx = it * 256 + t;          // float4 index, 2048 total
        int row  = fidx >> 5;             // 32 float4 per row
        int c4   = fidx & 31;
        const float4 v = *(const float4*)(edge_rbf + (e0 + row) * NF + c4 * 4);
        bf16x4 b;
        b[0] = (__bf16)v.x; b[1] = (__bf16)v.y; b[2] = (__bf16)v.z; b[3] = (__bf16)v.w;
        *(bf16x4*)&Ash[row][c4 * 4] = b;
    }
    __syncthreads();

    const int w = t >> 6, l = t & 63;
    const int er = l & 15, quad = l >> 4;

    // A-frags: A[m=lane&15][k=quad*8+j], one per 32-wide k-step
    bf16x8 afrag[4];
    #pragma unroll
    for (int s = 0; s < 4; ++s)
        afrag[s] = *(const bf16x8*)&Ash[16 * w + er][s * 32 + quad * 8];

    floatx4 acc[24];
    #pragma unroll
    for (int ct = 0; ct < 24; ++ct) acc[ct] = (floatx4){0.f, 0.f, 0.f, 0.f};

    #pragma unroll
    for (int ct = 0; ct < 24; ++ct) {
        #pragma unroll
        for (int s = 0; s < 4; ++s) {
            // B[k][n]: n = 16*ct + (lane&15), k = s*32 + quad*8 + j  (16B contig)
            bf16x8 bfrag = *(const bf16x8*)(WeT + (size_t)(16 * ct + er) * NF + s * 32 + quad * 8);
            acc[ct] = __builtin_amdgcn_mfma_f32_16x16x32_bf16(afrag[s], bfrag, acc[ct], 0, 0, 0);
        }
    }

    // Epilogue. C/D: col = lane&15 (-> cc = 16*ct+er), row = quad*4 + reg (-> edge)
    #pragma unroll
    for (int r = 0; r < 4; ++r) {
        const int  el = 16 * w + quad * 4 + r;
        const long e  = e0 + el;
        const int  j  = eidx[e];
        const int  i  = eidx[N_EDGES + e];
        const float ev0 = edge_vector[e * 3 + 0];
        const float ev1 = edge_vector[e * 3 + 1];
        const float ev2 = edge_vector[e * 3 + 2];
        const float* xh = x_h + (size_t)j * C3;
        const float* vj = vec + (size_t)j * 3 * HID;
        float* dx = d_x  + (size_t)i * HID;
        float* dv = d_vec + (size_t)i * 3 * HID;
        #pragma unroll
        for (int ct = 0; ct < 8; ++ct) {
            const int cc = ct * 16 + er;
            const float rbf1 = acc[ct][r]      + be[cc];
            const float rbf2 = acc[ct + 8][r]  + be[cc + 128];
            const float rbf3 = acc[ct + 16][r] + be[cc + 256];
            const float x1 = xh[cc]       * rbf1 * INV_SQRT3;
            const float x2 = xh[cc + 128] * rbf2 * INV_SQRT3;
            const float x3 = xh[cc + 256] * rbf3 * INV_SQRT3;
            unsafeAtomicAdd(dx + cc, x3);
            unsafeAtomicAdd(dv + cc,       (x1 * vj[cc]       + x2 * ev0) * INV_SQRTH);
            unsafeAtomicAdd(dv + 128 + cc, (x1 * vj[128 + cc] + x2 * ev1) * INV_SQRTH);
            unsafeAtomicAdd(dv + 256 + cc, (x1 * vj[256 + cc] + x2 * ev2) * INV_SQRTH);
        }
    }
}

// ---------------------------------------------------------------------------
extern "C" void kernel_launch(void* const* d_in, const int* in_sizes, int n_in,
                              void* d_out, int out_size, void* d_ws, size_t ws_size,
                              hipStream_t stream) {
    const float* x    = (const float*)d_in[0];
    const float* vec  = (const float*)d_in[1];
    const float* erbf = (const float*)d_in[2];
    const float* evec = (const float*)d_in[3];
    const int*   eidx = (const int*)d_in[4];
    const float* W1   = (const float*)d_in[5];
    const float* b1   = (const float*)d_in[6];
    const float* W2   = (const float*)d_in[7];
    const float* b2   = (const float*)d_in[8];
    const float* We   = (const float*)d_in[9];
    const float* be   = (const float*)d_in[10];

    float* out   = (float*)d_out;
    float* d_x   = out;                                  // [N, H]
    float* d_vec = out + (size_t)N_NODES * HID;          // [N, 3, H]

    // workspace: x_h f32 [N][384] (76.8 MB) then WeT bf16 [384][128] (96 KB)
    float*  x_h = (float*)d_ws;
    __bf16* WeT = (__bf16*)((char*)d_ws + (size_t)N_NODES * C3 * sizeof(float));

    hipMemsetAsync(d_out, 0, (size_t)out_size * sizeof(float), stream);
    cast_weT<<<(C3 * NF) / 256, 256, 0, stream>>>(We, WeT);
    node_mlp<<<N_NODES / 4, 256, 0, stream>>>(x, W1, b1, W2, b2, x_h);
    edge_kernel<<<N_EDGES / 64, 256, 0, stream>>>(erbf, WeT, be, x_h, vec, evec, eidx,
                                                  d_x, d_vec);
}

// Round 2
// 1906.897 us; speedup vs baseline: 1.3949x; 1.3949x over previous
//
#include <hip/hip_runtime.h>
#include <hip/hip_bf16.h>
#include <math.h>

#define N_NODES 50000
#define N_EDGES 800000
#define HID 128
#define NF 128
#define C3 384   // 3*H
#define SILU_SCALE (1.0f/0.6f)
#define INV_SQRT3 0.57735026918962576f
#define INV_SQRTH 0.08838834764831845f   // 1/sqrt(128)

// max groups: sum ceil(d/16) <= E/16 + N*15/16 = 50000 + 46875 = 96875
#define GMAX 96880            // padded to multiple of 4 (waves per block)
#define GBLOCKS (GMAX / 4)    // 24220
#define PERM_SLOTS (GMAX * 16)

typedef __bf16 bf16x8 __attribute__((ext_vector_type(8)));
typedef __bf16 bf16x4 __attribute__((ext_vector_type(4)));
typedef float  floatx4 __attribute__((ext_vector_type(4)));

// ---------------------------------------------------------------------------
// Cast + transpose We [128][384] f32 -> WeT [384][128] bf16 (B-operand layout)
// ---------------------------------------------------------------------------
__global__ void cast_weT(const float* __restrict__ We, __bf16* __restrict__ WeT) {
    int o = blockIdx.x * 256 + threadIdx.x;   // 49152 total
    int n = o / NF, k = o % NF;
    WeT[o] = (__bf16)We[k * C3 + n];
}

// ---------------------------------------------------------------------------
// Node MLP: 16 nodes per block of 384 threads. W2 column c owned by thread t,
// reused across 16 nodes -> W2 L2 traffic /4 vs round 1.
// ---------------------------------------------------------------------------
__global__ __launch_bounds__(384)
void node_mlp(const float* __restrict__ x,  const float* __restrict__ W1,
              const float* __restrict__ b1, const float* __restrict__ W2,
              const float* __restrict__ b2, float* __restrict__ x_h) {
    __shared__ float xs[16][HID];   // 8 KB
    __shared__ float hs[16][64];    // 4 KB
    const int t = threadIdx.x;
    const int base = blockIdx.x * 16;

    for (int f4 = t; f4 < 512; f4 += 384) {   // 16*128 floats = 512 float4
        float4 v = ((const float4*)(x + (size_t)base * HID))[f4];
        ((float4*)&xs[0][0])[f4] = v;
    }
    __syncthreads();
    for (int o = t; o < 1024; o += 384) {     // 16 nodes x 64 mid
        int g = o >> 6, m = o & 63;
        float sum = b1[m];
        #pragma unroll 8
        for (int k = 0; k < HID; ++k) sum += xs[g][k] * W1[k * 64 + m];
        float sig = 1.0f / (1.0f + __expf(-sum));
        hs[g][m] = sum * sig * SILU_SCALE;
    }
    __syncthreads();
    {
        float acc[16];
        #pragma unroll
        for (int n = 0; n < 16; ++n) acc[n] = b2[t];
        for (int k = 0; k < 64; ++k) {
            float w2 = W2[k * C3 + t];
            #pragma unroll
            for (int n = 0; n < 16; ++n) acc[n] += hs[n][k] * w2;
        }
        #pragma unroll
        for (int n = 0; n < 16; ++n) x_h[(size_t)(base + n) * C3 + t] = acc[n];
    }
}

// ---------------------------------------------------------------------------
// CSR build: histogram -> scan(+group tables) -> scatter
// ---------------------------------------------------------------------------
__global__ void hist_k(const int* __restrict__ eidx, int* __restrict__ counts) {
    int e = blockIdx.x * 256 + threadIdx.x;
    if (e < N_EDGES) atomicAdd(&counts[eidx[N_EDGES + e]], 1);
}

__global__ __launch_bounds__(1024)
void scan_k(const int* __restrict__ counts, int* __restrict__ first_group,
            int* __restrict__ group_node, int* __restrict__ group_valid,
            int* __restrict__ G_total) {
    __shared__ int ls[1024];
    const int t = threadIdx.x;
    const int CH = 49;                 // 1024*49 = 50176 >= 50000
    const int base = t * CH;
    int s = 0;
    for (int k = 0; k < CH; ++k) {
        int i = base + k;
        if (i < N_NODES) s += (counts[i] + 15) >> 4;
    }
    ls[t] = s;
    __syncthreads();
    for (int off = 1; off < 1024; off <<= 1) {   // Hillis-Steele inclusive
        int v = (t >= off) ? ls[t - off] : 0;
        __syncthreads();
        ls[t] += v;
        __syncthreads();
    }
    if (t == 1023) *G_total = ls[1023];
    int run = (t == 0) ? 0 : ls[t - 1];
    for (int k = 0; k < CH; ++k) {
        int i = base + k;
        if (i < N_NODES) {
            int d = counts[i];
            int ng = (d + 15) >> 4;
            first_group[i] = run;
            for (int q = 0; q < ng; ++q) {
                group_node[run + q]  = i;
                int rem = d - 16 * q;
                group_valid[run + q] = rem > 16 ? 16 : rem;
            }
            run += ng;
        }
    }
}

__global__ void scatter_k(const int* __restrict__ eidx,
                          const int* __restrict__ first_group,
                          int* __restrict__ cursor, int* __restrict__ perm) {
    int e = blockIdx.x * 256 + threadIdx.x;
    if (e >= N_EDGES) return;
    int i = eidx[N_EDGES + e];
    int pos = atomicAdd(&cursor[i], 1);
    perm[first_group[i] * 16 + pos] = e;
}

// ---------------------------------------------------------------------------
// Fused edge kernel over destination-sorted padded groups. One wave = one
// group = 16 edges, all with the same destination node i. Per-edge messages
// are reduced in-register across the 16 edges (r-accumulate + shfl_xor over
// quads) -> 512 atomic dwords per GROUP instead of per EDGE (11x fewer RMWs).
// ---------------------------------------------------------------------------
__global__ __launch_bounds__(256)
void edge_kernel(const float* __restrict__ edge_rbf,
                 const __bf16* __restrict__ WeT,
                 const float* __restrict__ be,
                 const float* __restrict__ x_h,
                 const float* __restrict__ vec,
                 const float* __restrict__ edge_vector,
                 const int*   __restrict__ eidx,
                 const int*   __restrict__ perm,
                 const int*   __restrict__ group_node,
                 const int*   __restrict__ group_valid,
                 const int*   __restrict__ G_total,
                 float* __restrict__ d_x, float* __restrict__ d_vec) {
    __shared__ __bf16 Ash[64][136];   // pad 8: quad-stride 272B -> free 2-way
    __shared__ int perm_s[64];
    const int t = threadIdx.x;
    const int g0 = blockIdx.x * 4;

    if (t < 64) perm_s[t] = perm[(size_t)g0 * 16 + t];
    __syncthreads();

    // Stage 64 gathered rows f32 -> bf16 (each row 512B contiguous)
    #pragma unroll
    for (int it = 0; it < 8; ++it) {
        int fidx = it * 256 + t;
        int row  = fidx >> 5;
        int c4   = fidx & 31;
        const float4 v = *(const float4*)(edge_rbf + (size_t)perm_s[row] * NF + c4 * 4);
        bf16x4 b;
        b[0] = (__bf16)v.x; b[1] = (__bf16)v.y; b[2] = (__bf16)v.z; b[3] = (__bf16)v.w;
        *(bf16x4*)&Ash[row][c4 * 4] = b;
    }
    __syncthreads();

    const int w = t >> 6, l = t & 63;
    const int er = l & 15, quad = l >> 4;
    const int g = g0 + w;
    if (g >= *G_total) return;

    const int i_node = group_node[g];
    const int nval   = group_valid[g];

    bf16x8 afrag[4];
    #pragma unroll
    for (int s = 0; s < 4; ++s)
        afrag[s] = *(const bf16x8*)&Ash[16 * w + er][s * 32 + quad * 8];

    // Per-(quad,r) edge scalars
    int jj[4]; float ev0[4], ev1[4], ev2[4];
    #pragma unroll
    for (int r = 0; r < 4; ++r) {
        int e = perm_s[16 * w + quad * 4 + r];
        jj[r]  = eidx[e];
        ev0[r] = edge_vector[(size_t)e * 3 + 0];
        ev1[r] = edge_vector[(size_t)e * 3 + 1];
        ev2[r] = edge_vector[(size_t)e * 3 + 2];
    }

    float* dxp = d_x  + (size_t)i_node * HID;
    float* dvp = d_vec + (size_t)i_node * 3 * HID;

    #pragma unroll
    for (int ct = 0; ct < 8; ++ct) {
        floatx4 a1 = (floatx4){0.f,0.f,0.f,0.f};
        floatx4 a2 = (floatx4){0.f,0.f,0.f,0.f};
        floatx4 a3 = (floatx4){0.f,0.f,0.f,0.f};
        #pragma unroll
        for (int s = 0; s < 4; ++s) {
            const __bf16* bb = WeT + (size_t)(16 * ct + er) * NF + s * 32 + quad * 8;
            a1 = __builtin_amdgcn_mfma_f32_16x16x32_bf16(afrag[s], *(const bf16x8*)bb, a1, 0, 0, 0);
            a2 = __builtin_amdgcn_mfma_f32_16x16x32_bf16(afrag[s], *(const bf16x8*)(bb + 128 * NF), a2, 0, 0, 0);
            a3 = __builtin_amdgcn_mfma_f32_16x16x32_bf16(afrag[s], *(const bf16x8*)(bb + 256 * NF), a3, 0, 0, 0);
        }
        const int cc = ct * 16 + er;
        const float be1 = be[cc], be2 = be[cc + 128], be3 = be[cc + 256];
        float p0 = 0.f, p1 = 0.f, p2 = 0.f, p3 = 0.f;
        #pragma unroll
        for (int r = 0; r < 4; ++r) {
            const float* xh = x_h + (size_t)jj[r] * C3;
            const float* vj = vec + (size_t)jj[r] * 3 * HID;
            float rbf1 = a1[r] + be1;
            float rbf2 = a2[r] + be2;
            float rbf3 = a3[r] + be3;
            float x1 = xh[cc]       * rbf1 * INV_SQRT3;
            float x2 = xh[cc + 128] * rbf2 * INV_SQRT3;
            float x3 = xh[cc + 256] * rbf3 * INV_SQRT3;
            if ((quad * 4 + r) >= nval) { x1 = 0.f; x2 = 0.f; x3 = 0.f; }
            p0 += x3;
            p1 += x1 * vj[cc]       + x2 * ev0[r];
            p2 += x1 * vj[cc + 128] + x2 * ev1[r];
            p3 += x1 * vj[cc + 256] + x2 * ev2[r];
        }
        // Reduce 16 edges: r-loop did 4, now across the 4 quads
        p0 += __shfl_xor(p0, 16, 64); p0 += __shfl_xor(p0, 32, 64);
        p1 += __shfl_xor(p1, 16, 64); p1 += __shfl_xor(p1, 32, 64);
        p2 += __shfl_xor(p2, 16, 64); p2 += __shfl_xor(p2, 32, 64);
        p3 += __shfl_xor(p3, 16, 64); p3 += __shfl_xor(p3, 32, 64);
        if (quad == (ct & 3)) {   // spread atomic issue across quads
            unsafeAtomicAdd(dxp + cc, p0);
            unsafeAtomicAdd(dvp + cc,       p1 * INV_SQRTH);
            unsafeAtomicAdd(dvp + cc + 128, p2 * INV_SQRTH);
            unsafeAtomicAdd(dvp + cc + 256, p3 * INV_SQRTH);
        }
    }
}

// ---------------------------------------------------------------------------
extern "C" void kernel_launch(void* const* d_in, const int* in_sizes, int n_in,
                              void* d_out, int out_size, void* d_ws, size_t ws_size,
                              hipStream_t stream) {
    const float* x    = (const float*)d_in[0];
    const float* vec  = (const float*)d_in[1];
    const float* erbf = (const float*)d_in[2];
    const float* evec = (const float*)d_in[3];
    const int*   eidx = (const int*)d_in[4];
    const float* W1   = (const float*)d_in[5];
    const float* b1   = (const float*)d_in[6];
    const float* W2   = (const float*)d_in[7];
    const float* b2   = (const float*)d_in[8];
    const float* We   = (const float*)d_in[9];
    const float* be   = (const float*)d_in[10];

    float* out   = (float*)d_out;
    float* d_x   = out;                              // [N, H]
    float* d_vec = out + (size_t)N_NODES * HID;      // [N, 3, H]

    // ---- workspace layout (all 256B-aligned) ----
    char* p = (char*)d_ws;
    float*  x_h        = (float*)p;  p += (size_t)N_NODES * C3 * 4;     // 76.8 MB
    __bf16* WeT        = (__bf16*)p; p += (size_t)C3 * NF * 2;          // 96 KB
    int* first_group   = (int*)p;    p += 50176 * 4;
    int* group_node    = (int*)p;    p += (GMAX + 16) * 4;
    int* group_valid   = (int*)p;    p += (GMAX + 16) * 4;
    int* G_total       = (int*)p;    p += 256;
    // zero-initialized region: counts, cursor, perm (one memset)
    char* zbase        = p;
    int* counts        = (int*)p;    p += 50176 * 4;
    int* cursor        = (int*)p;    p += 50176 * 4;
    int* perm          = (int*)p;    p += (size_t)PERM_SLOTS * 4;       // 6.2 MB
    size_t zbytes      = (size_t)(p - zbase);

    hipMemsetAsync(zbase, 0, zbytes, stream);
    hipMemsetAsync(d_out, 0, (size_t)out_size * sizeof(float), stream);

    cast_weT<<<(C3 * NF) / 256, 256, 0, stream>>>(We, WeT);
    node_mlp<<<N_NODES / 16, 384, 0, stream>>>(x, W1, b1, W2, b2, x_h);
    hist_k<<<(N_EDGES + 255) / 256, 256, 0, stream>>>(eidx, counts);
    scan_k<<<1, 1024, 0, stream>>>(counts, first_group, group_node, group_valid, G_total);
    scatter_k<<<(N_EDGES + 255) / 256, 256, 0, stream>>>(eidx, first_group, cursor, perm);
    edge_kernel<<<GBLOCKS, 256, 0, stream>>>(erbf, WeT, be, x_h, vec, evec, eidx,
                                             perm, group_node, group_valid, G_total,
                                             d_x, d_vec);
}